// Round 15
// baseline (897.343 us; speedup 1.0000x reference)
//
#include <hip/hip_runtime.h>
#include <hip/hip_bf16.h>

#define B_ 2
#define S_ 2048
#define D_ 512
#define H_ 8
#define L_ 6
#define F_ 2048
#define HD_ 64
#define M_ 4096
#define OFF_ 4999
#define NREL_ 9999

typedef short s8v __attribute__((ext_vector_type(8)));
typedef float f4v __attribute__((ext_vector_type(4)));

enum { MODE_BF16 = 0, MODE_RES = 1, MODE_GELU = 2 };

__device__ __forceinline__ short f2bf(float f) {
  unsigned u = __float_as_uint(f);
  unsigned r = (u + 0x7fffu + ((u >> 16) & 1u)) >> 16;
  return (short)r;
}

__device__ __forceinline__ float exp2fast(float x) {
  float r;
  asm("v_exp_f32 %0, %1" : "=v"(r) : "v"(x));
  return r;
}

__device__ __forceinline__ int cvt_pk_bf16(float lo, float hi) {
  int r;
  asm("v_cvt_pk_bf16_f32 %0, %1, %2" : "=v"(r) : "v"(lo), "v"(hi));
  return r;
}

__device__ __forceinline__ void gload16(const void* g, const void* l) {
  __builtin_amdgcn_global_load_lds((const __attribute__((address_space(1))) unsigned int*)g,
                                   (__attribute__((address_space(3))) unsigned int*)l,
                                   16, 0, 0);
}

// ---------------- weight transpose: src fp32 (K,N) -> dst bf16 (N,K) -------
__global__ void transpose_kernel(const float* __restrict__ src, short* __restrict__ dst,
                                 int K, int N, long srcBS, long dstBS, int rowOff)
{
  __shared__ float t[32][33];
  int tx = threadIdx.x, ty = threadIdx.y;  // block (32,8)
  int n0 = blockIdx.x * 32, k0 = blockIdx.y * 32, l = blockIdx.z;
  const float* s = src + (size_t)l * srcBS;
  short* d = dst + (size_t)l * dstBS;
  for (int j = 0; j < 4; ++j)
    t[ty + j*8][tx] = s[(size_t)(k0 + ty + j*8) * N + n0 + tx];
  __syncthreads();
  for (int j = 0; j < 4; ++j)
    d[(size_t)(rowOff + n0 + ty + j*8) * K + k0 + tx] = f2bf(t[tx][ty + j*8]);
}

__global__ void packb_kernel(const float* __restrict__ bq, const float* __restrict__ bk,
                             const float* __restrict__ bv, float* __restrict__ bqkv)
{
  int i = blockIdx.x * 256 + threadIdx.x;
  if (i >= L_ * 1536) return;
  int l = i / 1536, j = i % 1536;
  float v = (j < 512) ? bq[l*512 + j] : (j < 1024) ? bk[l*512 + j - 512] : bv[l*512 + j - 1024];
  bqkv[i] = v;
}

// ---- bias table transpose + pre-scale by log2(e): exp2-domain softmax -----
__global__ void tabt_kernel(const float* __restrict__ tab, float* __restrict__ tabT)
{
  int i = blockIdx.x * 256 + threadIdx.x;
  if (i >= L_ * H_ * NREL_) return;
  int l = i / (H_ * NREL_), rem = i % (H_ * NREL_);
  int h = rem / NREL_, idx = rem % NREL_;
  tabT[i] = tab[((size_t)l * NREL_ + idx) * H_ + h] * 1.44269504f;
}

// ---------------- spk_emb @ Wspk + bspk: grid (B_, 8), k-split + LDS reduce -
__global__ __launch_bounds__(256) void spk_kernel(const float* __restrict__ spk,
                                                  const float* __restrict__ Wspk,
                                                  const float* __restrict__ bspk,
                                                  float* __restrict__ sproj)
{
  __shared__ float red[4][64];
  int b = blockIdx.x, nb = blockIdx.y;
  int dl = threadIdx.x & 63, kc = threadIdx.x >> 6;
  int d = nb * 64 + dl;
  const float* sprow = spk + b * D_;
  float a0 = 0.f, a1 = 0.f;
  int kbeg = kc * 128;
  for (int k = kbeg; k < kbeg + 128; k += 2) {
    a0 += sprow[k]     * Wspk[(size_t)k * D_ + d];
    a1 += sprow[k + 1] * Wspk[(size_t)(k + 1) * D_ + d];
  }
  red[kc][dl] = a0 + a1;
  __syncthreads();
  if (kc == 0)
    sproj[b*D_ + d] = red[0][dl] + red[1][dl] + red[2][dl] + red[3][dl] + bspk[d];
}

// ---------------- prologue: x + PE + cond encodings -> X fp32 --------------
__global__ __launch_bounds__(256) void prologue_kernel(
    const float* __restrict__ x, const float* __restrict__ f0, const float* __restrict__ sp,
    const float* __restrict__ ap, const float* __restrict__ Wf0, const float* __restrict__ bf0,
    const float* __restrict__ Wsp, const float* __restrict__ bsp,
    const float* __restrict__ Wap, const float* __restrict__ bap,
    const float* __restrict__ sproj, float* __restrict__ X)
{
  int row = blockIdx.x, tid = threadIdx.x;
  int b = row >> 11, s = row & 2047;
  float vf0 = f0[row], vsp = sp[row], vap = ap[row];
  for (int j = 0; j < 2; ++j) {
    int d = tid + j * 256;
    int i = d >> 1;
    float div = expf((float)(2*i) * -0.01798894603f);  // -ln(10000)/512
    float arg = (float)s * div;
    float pe = (d & 1) ? cosf(arg) : sinf(arg);
    float v = x[(size_t)row*D_ + d] + pe
            + vf0*Wf0[d] + bf0[d] + vsp*Wsp[d] + bsp[d] + vap*Wap[d] + bap[d]
            + sproj[b*D_ + d];
    X[(size_t)row*D_ + d] = v;
  }
}

// ---------------- layernorm: X fp32 row -> bf16 (or fp32 final) ------------
__global__ __launch_bounds__(256) void ln_kernel(
    const float* __restrict__ X, const float* __restrict__ g, const float* __restrict__ bta,
    short* __restrict__ outB, float* __restrict__ outF, int f32out)
{
  __shared__ float red[8];
  int row = blockIdx.x, tid = threadIdx.x;
  const float* xr = X + (size_t)row * D_;
  float v0 = xr[tid], v1 = xr[tid + 256];
  float s = v0 + v1, q = v0*v0 + v1*v1;
  for (int off = 1; off < 64; off <<= 1) { s += __shfl_xor(s, off); q += __shfl_xor(q, off); }
  int w = tid >> 6;
  if ((tid & 63) == 0) { red[w*2] = s; red[w*2 + 1] = q; }
  __syncthreads();
  s = red[0] + red[2] + red[4] + red[6];
  q = red[1] + red[3] + red[5] + red[7];
  float mean = s * (1.0f / D_);
  float var = q * (1.0f / D_) - mean * mean;
  float rstd = rsqrtf(var + 1e-5f);
  float o0 = (v0 - mean) * rstd * g[tid] + bta[tid];
  float o1 = (v1 - mean) * rstd * g[tid + 256] + bta[tid + 256];
  if (f32out) {
    outF[(size_t)row*D_ + tid] = o0; outF[(size_t)row*D_ + tid + 256] = o1;
  } else {
    outB[(size_t)row*D_ + tid] = f2bf(o0); outB[(size_t)row*D_ + tid + 256] = f2bf(o1);
  }
}

// ---------------- bf16 MFMA GEMM 128x64 (qkv/ffn1: 3-4 blocks/CU) ----------
// Round-22 (verified, -105us): MODE_RES z=1, plain RMW X[idx]+=acc.
template<int MODE>
__device__ __forceinline__ void gemm_body(
    const short* __restrict__ A, const short* __restrict__ Wt,
    const float* __restrict__ bias, int K, int N,
    float* outF, short* outB)
{
  __shared__ short sA[2][4096];  // [panel][128 rows][32 k]
  __shared__ short sB[2][2048];  // [panel][64 rows][32 k]
  const int tid = threadIdx.x;
  const int w = tid >> 6, lane = tid & 63;
  const int col = lane & 15, quad = lane >> 4;
  const int m0 = blockIdx.x * 128, n0 = blockIdx.y * 64;
  const int nkt = K >> 6;

  const int rowT = tid >> 2, kcA = tid & 3;
  const size_t kc8 = kcA * 8;

  f4v acc[2][4] = {};
  for (int kt = 0; kt < nkt; ++kt) {
    const int k0 = kt * 64;
    __syncthreads();
    for (int p = 0; p < 2; ++p) {
      gload16(A + (size_t)(m0 + rowT) * K + k0 + p*32 + kc8,       &sA[p][(w*16) * 32]);
      gload16(A + (size_t)(m0 + 64 + rowT) * K + k0 + p*32 + kc8,  &sA[p][(64 + w*16) * 32]);
      gload16(Wt + (size_t)(n0 + rowT) * K + k0 + p*32 + kc8,      &sB[p][(w*16) * 32]);
    }
    __syncthreads();
    for (int p = 0; p < 2; ++p) {
      s8v af[2], bfr[4];
      for (int mt = 0; mt < 2; ++mt)
        af[mt] = *(const s8v*)&sA[p][(w*32 + mt*16 + col) * 32 + quad * 8];
      for (int nt = 0; nt < 4; ++nt)
        bfr[nt] = *(const s8v*)&sB[p][(nt*16 + col) * 32 + quad * 8];
      for (int mt = 0; mt < 2; ++mt)
        for (int nt = 0; nt < 4; ++nt)
          acc[mt][nt] = __builtin_amdgcn_mfma_f32_16x16x32_bf16(af[mt], bfr[nt], acc[mt][nt], 0, 0, 0);
    }
  }

  const float qsc = (MODE == MODE_BF16 && n0 < 512) ? 0.18033688f : 1.0f;  // 0.125*log2e
  float bz[4];
  for (int nt = 0; nt < 4; ++nt)
    bz[nt] = bias[n0 + nt*16 + col];
  for (int mt = 0; mt < 2; ++mt) {
    int mbase = m0 + w*32 + mt*16 + quad*4;
    for (int nt = 0; nt < 4; ++nt) {
      int n = n0 + nt*16 + col;
      for (int r = 0; r < 4; ++r) {
        float v = acc[mt][nt][r] + bz[nt];
        size_t idx = (size_t)(mbase + r) * N + n;
        if (MODE == MODE_RES) {
          outF[idx] = outF[idx] + v;
        } else if (MODE == MODE_GELU) {
          outB[idx] = f2bf(0.5f * v * (1.0f + erff(v * 0.70710678118f)));
        } else {
          outB[idx] = f2bf(v * qsc);
        }
      }
    }
  }
}

// ---------------- bf16 MFMA GEMM 64x64 (o/ffn2, verified round-24: -40us) --
// 2 blocks/CU: second resident block hides the other's barrier drain.
template<int MODE>
__device__ __forceinline__ void gemm_body64(
    const short* __restrict__ A, const short* __restrict__ Wt,
    const float* __restrict__ bias, int K, int N,
    float* outF, short* outB)
{
  __shared__ short sA[2][2048];  // [panel][64 rows][32 k]
  __shared__ short sB[2][2048];  // [panel][64 rows][32 k]
  const int tid = threadIdx.x;
  const int w = tid >> 6, lane = tid & 63;
  const int col = lane & 15, quad = lane >> 4;
  const int m0 = blockIdx.x * 64, n0 = blockIdx.y * 64;
  const int nkt = K >> 6;

  const int rowT = tid >> 2, kcA = tid & 3;
  const size_t kc8 = kcA * 8;

  f4v acc[4] = {};
  for (int kt = 0; kt < nkt; ++kt) {
    const int k0 = kt * 64;
    __syncthreads();
    for (int p = 0; p < 2; ++p) {
      gload16(A + (size_t)(m0 + rowT) * K + k0 + p*32 + kc8,   &sA[p][(w*16) * 32]);
      gload16(Wt + (size_t)(n0 + rowT) * K + k0 + p*32 + kc8,  &sB[p][(w*16) * 32]);
    }
    __syncthreads();
    for (int p = 0; p < 2; ++p) {
      s8v af = *(const s8v*)&sA[p][(w*16 + col) * 32 + quad * 8];
      s8v b0 = *(const s8v*)&sB[p][( 0 + col) * 32 + quad * 8];
      s8v b1 = *(const s8v*)&sB[p][(16 + col) * 32 + quad * 8];
      s8v b2 = *(const s8v*)&sB[p][(32 + col) * 32 + quad * 8];
      s8v b3 = *(const s8v*)&sB[p][(48 + col) * 32 + quad * 8];
      acc[0] = __builtin_amdgcn_mfma_f32_16x16x32_bf16(af, b0, acc[0], 0, 0, 0);
      acc[1] = __builtin_amdgcn_mfma_f32_16x16x32_bf16(af, b1, acc[1], 0, 0, 0);
      acc[2] = __builtin_amdgcn_mfma_f32_16x16x32_bf16(af, b2, acc[2], 0, 0, 0);
      acc[3] = __builtin_amdgcn_mfma_f32_16x16x32_bf16(af, b3, acc[3], 0, 0, 0);
    }
  }

  int mbase = m0 + w*16 + quad*4;
  for (int nt = 0; nt < 4; ++nt) {
    int n = n0 + nt*16 + col;
    float bz = bias[n];
    for (int r = 0; r < 4; ++r) {
      float v = acc[nt][r] + bz;
      size_t idx = (size_t)(mbase + r) * N + n;
      if (MODE == MODE_RES) {
        outF[idx] = outF[idx] + v;
      } else if (MODE == MODE_GELU) {
        outB[idx] = f2bf(0.5f * v * (1.0f + erff(v * 0.70710678118f)));
      } else {
        outB[idx] = f2bf(v);
      }
    }
  }
}

__global__ __launch_bounds__(256) void gemm_qkv_kernel(
    const short* __restrict__ A, const short* __restrict__ Wt,
    const float* __restrict__ bias, float* outF, short* outB)
{ gemm_body<MODE_BF16>(A, Wt, bias, 512, 1536, outF, outB); }

__global__ __launch_bounds__(256) void gemm_o_kernel(
    const short* __restrict__ A, const short* __restrict__ Wt,
    const float* __restrict__ bias, float* outF, short* outB)
{ gemm_body64<MODE_RES>(A, Wt, bias, 512, 512, outF, outB); }

__global__ __launch_bounds__(256) void gemm_ffn1_kernel(
    const short* __restrict__ A, const short* __restrict__ Wt,
    const float* __restrict__ bias, float* outF, short* outB)
{ gemm_body<MODE_GELU>(A, Wt, bias, 512, 2048, outF, outB); }

__global__ __launch_bounds__(256) void gemm_ffn2_kernel(
    const short* __restrict__ A, const short* __restrict__ Wt,
    const float* __restrict__ bias, float* outF, short* outB)
{ gemm_body64<MODE_RES>(A, Wt, bias, 2048, 512, outF, outB); }

// ---------------- V transpose: QKV V-part (b,s,h,hd) -> Vt (b,h,hd,s) ------
__global__ __launch_bounds__(256) void vtrans_kernel(const short* __restrict__ QKV,
                                                     short* __restrict__ Vt)
{
  __shared__ short t[64 * 72];
  int tid = threadIdx.x;
  int s0 = blockIdx.x * 64, bh = blockIdx.y;
  int b = bh >> 3, h = bh & 7;
  for (int it = 0; it < 2; ++it) {
    int c = it * 256 + tid;
    int sR = c >> 3, hc = c & 7;
    s8v v = *(const s8v*)(QKV + (size_t)(b*S_ + s0 + sR) * 1536 + 1024 + h*64 + hc*8);
    *(s8v*)&t[sR * 72 + hc * 8] = v;
  }
  __syncthreads();
  for (int it = 0; it < 2; ++it) {
    int c = it * 256 + tid;
    int hd = c >> 3, sc = c & 7;
    s8v v;
    for (int j = 0; j < 8; ++j) v[j] = t[(sc*8 + j) * 72 + hd];
    *(s8v*)(Vt + (size_t)(bh*64 + hd) * S_ + s0 + sc*8) = v;
  }
}

// ---------------- flash attention v11 (round-25: QBLK 128->64, 2 blocks/CU)
// Rounds 22/24 proved the occupancy-via-2-independent-blocks lever on GEMMs
// (each time ~ predicted); round-23 showed flash traffic cuts are neutral ->
// the exposed cost is the single barrier domain (1 block/CU, every kt's
// staging drain blocks all resident waves). v11 = v10's exact per-wave
// structure with QBLK=64: 256 threads / 4 waves (2 k-teams x 2 qg of 32
// rows), grid (16, 32) = 512 blocks = 2/CU -> two independent barrier
// domains per CU overlap each other's drains. Staging: each thread covers 2
// slots via named rk0/rk1/rv0/rv1 prefetch regs (rule #20). Per-CU MFMA work
// unchanged; K/V global reads 2x but L2-hot (256KB/bh).
#define SM2(ST, Ba, Bb, Bc, Bd, LS, slotQ, kpos) do {               \
    float p0 = exp2fast(ST[0] + Ba);                                \
    float p1 = exp2fast(ST[1] + Bb);                                \
    float p2 = exp2fast(ST[2] + Bc);                                \
    float p3 = exp2fast(ST[3] + Bd);                                \
    LS += (p0 + p1) + (p2 + p3);                                    \
    int2 pk;                                                        \
    pk.x = cvt_pk_bf16(p0, p1);                                     \
    pk.y = cvt_pk_bf16(p2, p3);                                     \
    *(int2*)&sAll[10240 + w*1280 + (slotQ)*640 + col*40 + (kpos) + quad*4] = pk; \
  } while (0)

#define MFMA16(A, Bv, C) C = __builtin_amdgcn_mfma_f32_16x16x32_bf16(A, Bv, C, 0, 0, 0)

__global__ __launch_bounds__(256) void flash_kernel(
    const short* __restrict__ QKV, const short* __restrict__ Vt,
    const float* __restrict__ tabT, short* __restrict__ AO)
{
  // sK [0,5120) = [team2][hc2][kk32][40]; sV [5120,10240) = [ko2][hd64][40];
  // sP [10240,15360) = [w4][qg2'2][q16][40]. sComb reuses [0,16384B) post-loop.
  __shared__ __attribute__((aligned(16))) short sAll[15360];
  __shared__ float sRowA[128];   // [team2][qg2][qg2'2][16]

  const int tid = threadIdx.x;
  const int w = tid >> 6, lane = tid & 63;
  const int col = lane & 15, quad = lane >> 4;
  const int team = w >> 1, qg = w & 1;
  const int qbase = qg * 32;
  const int bh = blockIdx.x, qt = blockIdx.y;
  const int b = bh >> 3, h = bh & 7;
  const int q0 = qt * 64;
  const int nkt = S_ / 64;
  const float* tabh = tabT + (size_t)h * NREL_;
  const float* tbB = tabh + (OFF_ - q0 - qbase - col + team*32 + quad*4);

  const short* gQ0 = QKV + (size_t)(b*S_ + q0 + qbase + col) * 1536 + h*64 + quad*8;
  s8v bQ00 = *(const s8v*)gQ0;
  s8v bQ01 = *(const s8v*)(gQ0 + 32);
  const short* gQ1 = gQ0 + 16*1536;
  s8v bQ10 = *(const s8v*)gQ1;
  s8v bQ11 = *(const s8v*)(gQ1 + 32);

  // staging: thread covers slots tid and tid+256 (hc halves / hd halves)
  const int c4 = tid & 3;
  const int kK = (tid >> 2) & 63;
  const short* gKa = QKV + (size_t)(b*S_ + kK) * 1536 + 512 + h*64 + c4*8;        // hc=0
  const short* gKb = gKa + 32;                                                     // hc=1
  short* dKa = &sAll[(kK >> 5)*2560 + 0*1280 + (kK & 31)*40 + c4*8];
  short* dKb = &sAll[(kK >> 5)*2560 + 1*1280 + (kK & 31)*40 + c4*8];
  const int c8 = tid & 7, hdVa = tid >> 3;          // hdVa in [0,32)
  const int hdVb = hdVa + 32;                        // [32,64)
  const short* gVa = Vt + (size_t)(bh*64 + hdVa) * S_ + c8*8;
  const short* gVb = Vt + (size_t)(bh*64 + hdVb) * S_ + c8*8;
  short* dVa = &sAll[5120 + (c8 >> 2)*2560 + hdVa*40 + (c8 & 3)*8];
  short* dVb = &sAll[5120 + (c8 >> 2)*2560 + hdVb*40 + (c8 & 3)*8];

  int4 rk0 = *(const int4*)gKa;
  int4 rk1 = *(const int4*)gKb;
  int4 rv0 = *(const int4*)gVa;
  int4 rv1 = *(const int4*)gVb;

  float lsum0 = 0.0f, lsum1 = 0.0f;
  f4v o00 = {}, o01 = {}, o02 = {}, o03 = {};
  f4v o10 = {}, o11 = {}, o12 = {}, o13 = {};

  const int kofs = team * 2560;
  const int vofs = 5120 + team * 2560;

  for (int kt = 0; kt < nkt; ++kt) {
    const float* tb = tbB + kt * 64;
    float bm0 = tb[-16], bm1 = tb[-15], bm2 = tb[-14], bm3 = tb[-13];
    float b00 = tb[0],   b01 = tb[1],   b02 = tb[2],   b03 = tb[3];
    float bp0 = tb[16],  bp1 = tb[17],  bp2 = tb[18],  bp3 = tb[19];
    __syncthreads();
    *(int4*)dKa = rk0;
    *(int4*)dKb = rk1;
    *(int4*)dVa = rv0;
    *(int4*)dVb = rv1;
    __syncthreads();
    if (kt + 1 < nkt) {
      rk0 = *(const int4*)(gKa + (size_t)(kt + 1) * 64 * 1536);
      rk1 = *(const int4*)(gKb + (size_t)(kt + 1) * 64 * 1536);
      rv0 = *(const int4*)(gVa + (kt + 1) * 64);
      rv1 = *(const int4*)(gVb + (kt + 1) * 64);
    }
    s8v ak00 = *(const s8v*)&sAll[kofs + 0*1280 + ( 0 + col)*40 + quad*8];
    s8v ak01 = *(const s8v*)&sAll[kofs + 1*1280 + ( 0 + col)*40 + quad*8];
    s8v ak10 = *(const s8v*)&sAll[kofs + 0*1280 + (16 + col)*40 + quad*8];
    s8v ak11 = *(const s8v*)&sAll[kofs + 1*1280 + (16 + col)*40 + quad*8];
    f4v st00 = {}, st01 = {}, st10 = {}, st11 = {};
    MFMA16(ak00, bQ00, st00); MFMA16(ak01, bQ01, st00);
    MFMA16(ak00, bQ10, st01); MFMA16(ak01, bQ11, st01);
    MFMA16(ak10, bQ00, st10); MFMA16(ak11, bQ01, st10);
    MFMA16(ak10, bQ10, st11); MFMA16(ak11, bQ11, st11);
    SM2(st00, b00, b01, b02, b03, lsum0, 0, 0);
    SM2(st01, bm0, bm1, bm2, bm3, lsum1, 1, 0);
    SM2(st10, bp0, bp1, bp2, bp3, lsum0, 0, 16);
    SM2(st11, b00, b01, b02, b03, lsum1, 1, 16);
    s8v aP0 = *(const s8v*)&sAll[10240 + w*1280 +   0 + col*40 + quad*8];
    s8v aP1 = *(const s8v*)&sAll[10240 + w*1280 + 640 + col*40 + quad*8];
    s8v bv0 = *(const s8v*)&sAll[vofs + ( 0 + col)*40 + quad*8];
    s8v bv1 = *(const s8v*)&sAll[vofs + (16 + col)*40 + quad*8];
    s8v bv2 = *(const s8v*)&sAll[vofs + (32 + col)*40 + quad*8];
    s8v bv3 = *(const s8v*)&sAll[vofs + (48 + col)*40 + quad*8];
    MFMA16(aP0, bv0, o00); MFMA16(aP0, bv1, o01);
    MFMA16(aP0, bv2, o02); MFMA16(aP0, bv3, o03);
    MFMA16(aP1, bv0, o10); MFMA16(aP1, bv1, o11);
    MFMA16(aP1, bv2, o12); MFMA16(aP1, bv3, o13);
  }

  // ---- cross-team combine ----
  lsum0 += __shfl_xor(lsum0, 16); lsum0 += __shfl_xor(lsum0, 32);
  lsum1 += __shfl_xor(lsum1, 16); lsum1 += __shfl_xor(lsum1, 32);
  __syncthreads();   // all waves done with sAll -> safe to reuse
  if (lane < 16) {
    sRowA[team*64 + qg*32 + lane]      = lsum0;
    sRowA[team*64 + qg*32 + 16 + lane] = lsum1;
  }
  f4v* sComb = (f4v*)sAll;
  if (team == 1) {
    sComb[(qg*8 + 0)*64 + lane] = o00;
    sComb[(qg*8 + 1)*64 + lane] = o01;
    sComb[(qg*8 + 2)*64 + lane] = o02;
    sComb[(qg*8 + 3)*64 + lane] = o03;
    sComb[(qg*8 + 4)*64 + lane] = o10;
    sComb[(qg*8 + 5)*64 + lane] = o11;
    sComb[(qg*8 + 6)*64 + lane] = o12;
    sComb[(qg*8 + 7)*64 + lane] = o13;
  }
  __syncthreads();
  if (team == 0) {
    int rbase = qg*32 + quad*4;
    float ra0 = sRowA[rbase+0] + sRowA[64+rbase+0];
    float ra1 = sRowA[rbase+1] + sRowA[64+rbase+1];
    float ra2 = sRowA[rbase+2] + sRowA[64+rbase+2];
    float ra3 = sRowA[rbase+3] + sRowA[64+rbase+3];
    float rb0 = sRowA[rbase+16+0] + sRowA[64+rbase+16+0];
    float rb1 = sRowA[rbase+16+1] + sRowA[64+rbase+16+1];
    float rb2 = sRowA[rbase+16+2] + sRowA[64+rbase+16+2];
    float rb3 = sRowA[rbase+16+3] + sRowA[64+rbase+16+3];
    short* aoRow = AO + (size_t)(b*S_ + q0 + qbase)*512 + h*64 + col;
#define WOUT(OV, qg2, nt, RA0, RA1, RA2, RA3) do {                       \
      f4v pp = OV + sComb[(qg*8 + (qg2)*4 + (nt))*64 + lane];            \
      aoRow[((qg2)*16 + quad*4 + 0)*512 + (nt)*16] = f2bf(pp[0] / RA0);  \
      aoRow[((qg2)*16 + quad*4 + 1)*512 + (nt)*16] = f2bf(pp[1] / RA1);  \
      aoRow[((qg2)*16 + quad*4 + 2)*512 + (nt)*16] = f2bf(pp[2] / RA2);  \
      aoRow[((qg2)*16 + quad*4 + 3)*512 + (nt)*16] = f2bf(pp[3] / RA3);  \
    } while (0)
    WOUT(o00, 0, 0, ra0, ra1, ra2, ra3);
    WOUT(o01, 0, 1, ra0, ra1, ra2, ra3);
    WOUT(o02, 0, 2, ra0, ra1, ra2, ra3);
    WOUT(o03, 0, 3, ra0, ra1, ra2, ra3);
    WOUT(o10, 1, 0, rb0, rb1, rb2, rb3);
    WOUT(o11, 1, 1, rb0, rb1, rb2, rb3);
    WOUT(o12, 1, 2, rb0, rb1, rb2, rb3);
    WOUT(o13, 1, 3, rb0, rb1, rb2, rb3);
#undef WOUT
  }
}

// ===========================================================================
extern "C" void kernel_launch(void* const* d_in, const int* in_sizes, int n_in,
                              void* d_out, int out_size, void* d_ws, size_t ws_size,
                              hipStream_t stream)
{
  const float* x    = (const float*)d_in[0];
  const float* f0   = (const float*)d_in[1];
  const float* sp   = (const float*)d_in[2];
  const float* ap   = (const float*)d_in[3];
  const float* spk  = (const float*)d_in[4];
  const float* Wf0  = (const float*)d_in[5];  const float* bf0  = (const float*)d_in[6];
  const float* Wsp  = (const float*)d_in[7];  const float* bsp  = (const float*)d_in[8];
  const float* Wap  = (const float*)d_in[9];  const float* bap  = (const float*)d_in[10];
  const float* Wspk = (const float*)d_in[11]; const float* bspk = (const float*)d_in[12];
  const float* Wq   = (const float*)d_in[13]; const float* bq   = (const float*)d_in[14];
  const float* Wk   = (const float*)d_in[15]; const float* bk   = (const float*)d_in[16];
  const float* Wv   = (const float*)d_in[17]; const float* bv   = (const float*)d_in[18];
  const float* Wo   = (const float*)d_in[19]; const float* bo   = (const float*)d_in[20];
  const float* ln1g = (const float*)d_in[21]; const float* ln1b = (const float*)d_in[22];
  const float* ln2g = (const float*)d_in[23]; const float* ln2b = (const float*)d_in[24];
  const float* W1   = (const float*)d_in[25]; const float* b1   = (const float*)d_in[26];
  const float* W2   = (const float*)d_in[27]; const float* b2   = (const float*)d_in[28];
  const float* tab  = (const float*)d_in[29];
  const float* gfin = (const float*)d_in[30]; const float* bfin = (const float*)d_in[31];

  char* p = (char*)d_ws;
  auto alloc = [&](size_t bytes) { char* r = p; p += (bytes + 255) & ~(size_t)255; return r; };
  short* WqkvT = (short*)alloc((size_t)L_ * 1536 * 512 * 2);
  short* WoT   = (short*)alloc((size_t)L_ * 512 * 512 * 2);
  short* W1T   = (short*)alloc((size_t)L_ * 2048 * 512 * 2);
  short* W2T   = (short*)alloc((size_t)L_ * 512 * 2048 * 2);
  float* bqkv  = (float*)alloc((size_t)L_ * 1536 * 4);
  float* X     = (float*)alloc((size_t)M_ * D_ * 4);
  short* Hb    = (short*)alloc((size_t)M_ * D_ * 2);
  short* AO    = (short*)alloc((size_t)M_ * D_ * 2);
  short* QKVb  = (short*)alloc((size_t)M_ * 1536 * 2);
  short* VtG   = (short*)alloc((size_t)B_ * H_ * HD_ * S_ * 2);
  short* H1b   = QKVb;  // alias: FFN hidden (M,F) reuses QKVb+VtG region (exactly 16 MB)
  float* sproj = (float*)alloc((size_t)B_ * D_ * 4);
  float* tabT  = (float*)alloc((size_t)L_ * H_ * NREL_ * 4);

  dim3 b256(256);
  dim3 tb(32, 8);
  packb_kernel<<<dim3((L_*1536 + 255)/256), b256, 0, stream>>>(bq, bk, bv, bqkv);
  tabt_kernel<<<dim3((L_*H_*NREL_ + 255)/256), b256, 0, stream>>>(tab, tabT);
  transpose_kernel<<<dim3(16, 16, L_), tb, 0, stream>>>(Wq, WqkvT, 512, 512, 512*512, 1536*512, 0);
  transpose_kernel<<<dim3(16, 16, L_), tb, 0, stream>>>(Wk, WqkvT, 512, 512, 512*512, 1536*512, 512);
  transpose_kernel<<<dim3(16, 16, L_), tb, 0, stream>>>(Wv, WqkvT, 512, 512, 512*512, 1536*512, 1024);
  transpose_kernel<<<dim3(16, 16, L_), tb, 0, stream>>>(Wo, WoT, 512, 512, 512*512, 512*512, 0);
  transpose_kernel<<<dim3(64, 16, L_), tb, 0, stream>>>(W1, W1T, 512, 2048, 512*2048, 2048*512, 0);
  transpose_kernel<<<dim3(16, 64, L_), tb, 0, stream>>>(W2, W2T, 2048, 512, 2048*512, 512*2048, 0);
  spk_kernel<<<dim3(B_, 8), b256, 0, stream>>>(spk, Wspk, bspk, sproj);
  prologue_kernel<<<dim3(M_), b256, 0, stream>>>(x, f0, sp, ap, Wf0, bf0, Wsp, bsp, Wap, bap, sproj, X);

  for (int l = 0; l < L_; ++l) {
    ln_kernel<<<dim3(M_), b256, 0, stream>>>(X, ln1g + l*D_, ln1b + l*D_, Hb, nullptr, 0);
    gemm_qkv_kernel<<<dim3(32, 24, 1), b256, 0, stream>>>(
        Hb, WqkvT + (size_t)l*1536*512, bqkv + l*1536, nullptr, QKVb);
    vtrans_kernel<<<dim3(S_/64, B_*H_), b256, 0, stream>>>(QKVb, VtG);
    flash_kernel<<<dim3(B_*H_, S_/64), dim3(256), 0, stream>>>(QKVb, VtG, tabT + (size_t)l*H_*NREL_, AO);
    gemm_o_kernel<<<dim3(64, 8, 1), b256, 0, stream>>>(
        AO, WoT + (size_t)l*512*512, bo + l*D_, X, nullptr);
    ln_kernel<<<dim3(M_), b256, 0, stream>>>(X, ln2g + l*D_, ln2b + l*D_, Hb, nullptr, 0);
    gemm_ffn1_kernel<<<dim3(32, 32, 1), b256, 0, stream>>>(
        Hb, W1T + (size_t)l*2048*512, b1 + l*F_, nullptr, H1b);
    gemm_ffn2_kernel<<<dim3(64, 8, 1), b256, 0, stream>>>(
        H1b, W2T + (size_t)l*512*2048, b2 + l*D_, X, nullptr);
  }
  ln_kernel<<<dim3(M_), b256, 0, stream>>>(X, gfin, bfin, nullptr, (float*)d_out, 1);
}